// Round 1
// baseline (102.859 us; speedup 1.0000x reference)
//
#include <hip/hip_runtime.h>
#include <hip/hip_bf16.h>

// MultiHeadLiftLayer:
//   y0 = x0 @ W[:128]  (per-node, 50000x8)
//   y1 = x0 @ W[128:]  (per-node, 50000x8)
//   edge_signal[e,h] = relu(y0[src[e],h] + y1[tgt[e],h])
//   out = cat([edge_signal, x_1], axis=1)   // (625000, 72) f32
//
// Kernel 1: per-node projection into d_ws (50000 x 16 floats, 3.2 MB).
//   layout: y[n*16 + slot], slot = half*8 + h  (half 0 -> W[:128], 1 -> W[128:])
// Kernel 2: streaming edge kernel, float4-flat over E*18 float4 per row.

#define NUM_NODES 50000
#define C0 128
#define HEADS 8
#define NODES_PER_BLK 16
#define XS_STRIDE 132   // 128 + 4 pad: breaks LDS bank aliasing across nodes

__global__ __launch_bounds__(256) void node_proj_kernel(
    const float* __restrict__ x0, const float* __restrict__ W,
    float* __restrict__ y, int num_nodes)
{
    __shared__ float Ws[2 * C0 * HEADS];          // 2048 floats = 8 KB
    __shared__ float xs[NODES_PER_BLK * XS_STRIDE];

    // stage W (coalesced)
    for (int i = threadIdx.x; i < 2 * C0 * HEADS; i += 256) Ws[i] = W[i];

    // stage 16 rows of x0 (coalesced: consecutive threads read consecutive floats)
    const int nodeBase = blockIdx.x * NODES_PER_BLK;
    for (int i = threadIdx.x; i < NODES_PER_BLK * C0; i += 256) {
        int r = i >> 7;          // local node
        int c = i & (C0 - 1);
        int n = nodeBase + r;
        xs[r * XS_STRIDE + c] = (n < num_nodes) ? x0[n * C0 + c] : 0.f;
    }
    __syncthreads();

    const int local = threadIdx.x >> 4;   // 0..15 local node
    const int slot  = threadIdx.x & 15;   // half*8 + h
    const int half  = slot >> 3;
    const int h     = slot & 7;

    const float* xr = &xs[local * XS_STRIDE];
    const float* Wr = &Ws[half * C0 * HEADS + h];

    float acc = 0.f;
    #pragma unroll 8
    for (int c = 0; c < C0; ++c)
        acc = fmaf(xr[c], Wr[c * HEADS], acc);

    const int n = nodeBase + local;
    if (n < num_nodes) y[n * 16 + slot] = acc;
}

// 72 f32 per output row = 18 float4. j4==0/1: heads; j4 in [2,18): x_1 row.
__global__ __launch_bounds__(256) void edge_out_kernel(
    const float* __restrict__ y, const float* __restrict__ x1,
    const int* __restrict__ adj, float* __restrict__ out, int E)
{
    const float4* __restrict__ yv  = (const float4*)y;   // 4 float4 per node
    const float4* __restrict__ x1v = (const float4*)x1;  // 16 float4 per edge
    float4* __restrict__ outv = (float4*)out;            // 18 float4 per edge

    const int total = E * 18;
    for (int i = blockIdx.x * blockDim.x + threadIdx.x; i < total;
         i += gridDim.x * blockDim.x) {
        const int e = i / 18;
        const int j = i - e * 18;
        float4 v;
        if (j >= 2) {
            v = x1v[e * 16 + (j - 2)];
        } else {
            const int s = adj[e];
            const int t = adj[E + e];
            const float4 a = yv[s * 4 + j];       // y0 half
            const float4 b = yv[t * 4 + 2 + j];   // y1 half
            v.x = fmaxf(a.x + b.x, 0.f);
            v.y = fmaxf(a.y + b.y, 0.f);
            v.z = fmaxf(a.z + b.z, 0.f);
            v.w = fmaxf(a.w + b.w, 0.f);
        }
        outv[i] = v;
    }
}

extern "C" void kernel_launch(void* const* d_in, const int* in_sizes, int n_in,
                              void* d_out, int out_size, void* d_ws, size_t ws_size,
                              hipStream_t stream) {
    const float* x0  = (const float*)d_in[0];
    const int*   adj = (const int*)d_in[1];   // JAX demotes int64->int32 (no x64)
    const float* x1  = (const float*)d_in[2];
    const float* W   = (const float*)d_in[3];
    float* out = (float*)d_out;
    float* y   = (float*)d_ws;                // 50000*16 floats = 3.2 MB

    const int E = in_sizes[1] / 2;            // 625000

    // Kernel 1: node projection. 16 nodes/block.
    {
        dim3 grid((NUM_NODES + NODES_PER_BLK - 1) / NODES_PER_BLK);
        node_proj_kernel<<<grid, 256, 0, stream>>>(x0, W, y, NUM_NODES);
    }
    // Kernel 2: streaming edge output.
    {
        const int total4 = E * 18;
        int blocks = (total4 + 255) / 256;
        if (blocks > 8192) blocks = 8192;
        edge_out_kernel<<<blocks, 256, 0, stream>>>(y, x1, adj, out, E);
    }
}